// Round 13
// baseline (889.049 us; speedup 1.0000x reference)
//
#include <hip/hip_runtime.h>
#include <cstdint>
#include <cstddef>

#define B_ 128
#define T_ 500
#define I_ 512
#define H_ 1024
#define O_ 11
#define BETA 0.9f
#define THRESH 1.0f
#define K2_ 1536  // 3 regions of 512: [xh*wh | xl*wh | xh*wl]
#define LDA 72

typedef __attribute__((ext_vector_type(4))) float f32x4;
typedef __attribute__((ext_vector_type(8))) short bf16x8;
typedef __attribute__((ext_vector_type(4))) unsigned int u32x4;

struct ScanSmem {
  int accL[H_];
  unsigned int listL[H_];
  unsigned int fcL[2];
  float red[H_];
  float part[352];
};
struct GemmSmem {
  alignas(16) unsigned short As[128 * LDA];
  alignas(16) unsigned short Bs[256 * LDA];
};
union FusedSmem { ScanSmem s; GemmSmem g; };

__device__ __forceinline__ unsigned short bf16_rne(float f) {
  unsigned int u = __float_as_uint(f);
  unsigned int r = u + 0x7FFFu + ((u >> 16) & 1u);
  return (unsigned short)(r >> 16);
}
__device__ __forceinline__ float bf16_to_f(unsigned short h) {
  return __uint_as_float(((unsigned int)h) << 16);
}

// ---------------- merged prep: blocks 0-255 build CSR; blocks 256+ build Wt -------------------
__global__ void k_prep(const float* __restrict__ W_rec, const float* __restrict__ mask,
                       const float* __restrict__ W_in,
                       unsigned int* __restrict__ csr, unsigned int* __restrict__ rowhi,
                       unsigned short* __restrict__ Wt) {
  int id = blockIdx.x;
  int tid = threadIdx.x;
  if (id < 256) {
    int r = id * 4 + (tid >> 6);
    int lane = tid & 63;
    unsigned cnt = 0;
    const float* mrow = mask + (size_t)r * H_;
    const float* wrow = W_rec + (size_t)r * H_;
    for (int c = 0; c < 16; ++c) {
      float m = mrow[c * 64 + lane];
      bool nz = (m != 0.f);
      unsigned long long bb = __ballot(nz);
      unsigned pos = cnt + (unsigned)__popcll(bb & ((1ull << lane) - 1ull));
      if (nz) {
        float w = wrow[c * 64 + lane] * m;
        int wi = __float2int_rn(w * 8388608.f);  // 2^23
        wi = wi > 2097151 ? 2097151 : (wi < -2097151 ? -2097151 : wi);
        if (pos < 128u) csr[((size_t)r << 7) + pos] = (((unsigned)wi) << 10) | (unsigned)(c * 64 + lane);
      }
      cnt += (unsigned)__popcll(bb);
    }
    for (unsigned p = (cnt > 128u ? 128u : cnt) + (unsigned)lane; p < 128u; p += 64u)
      csr[((size_t)r << 7) + p] = (p & 63u);
    if (lane == 0) rowhi[r] = (cnt > 64u) ? 1u : 0u;
  } else {
    int wid = id - 256;
    int n = wid / 6, kblk = wid - n * 6;
    int k2 = kblk * 256 + tid;
    int i = k2 & 511;
    int c = k2 >> 9;
    float w = W_in[i * H_ + n];
    unsigned short hi = bf16_rne(w);
    unsigned short v = (c == 2) ? bf16_rne(w - bf16_to_f(hi)) : hi;
    Wt[(size_t)n * K2_ + k2] = v;
  }
}

// ---------------- GEMM body: 1024 threads / 16 waves, 128x256 tile, 64x32 per wave ------------
__device__ __forceinline__ void gemm_body(const float* __restrict__ x,
                                          const unsigned short* __restrict__ Wt,
                                          float* __restrict__ drive, int t0, int Tc,
                                          int id, int tid,
                                          unsigned short* As, unsigned short* Bs) {
  int mt = (id >> 5) * 8 + (id & 7);  // XCD affinity: same mt -> ids equal mod 8
  int nt = (id >> 3) & 3;
  if (mt >= Tc) return;
  int lane = tid & 63, w = tid >> 6;
  int wr = w >> 3, wc = w & 7;  // 2 x 8 wave grid, each 64x32
  f32x4 acc[4][2] = {};
  int arow = tid >> 3, aoct = tid & 7;  // A stage: 128 rows x 8 thr x 8 f32
  int brow = tid >> 2, bq = tid & 3;    // B stage: 256 rows x 4 thr x 16 bf16
  int rr = mt * 128 + arow;
  int bb = rr / Tc, tt = rr - bb * Tc;
  const float* xrow = x + ((size_t)(bb * T_ + t0 + tt)) * I_ + aoct * 8;
  const unsigned short* wtrow = Wt + (size_t)(nt * 256 + brow) * K2_ + bq * 16;
  for (int kt = 0; kt < K2_ / 64; ++kt) {
    int creg = kt >> 3;         // 0:xh 1:xl 2:xh (wave-uniform)
    const float* ap = xrow + (kt & 7) * 64;
    float4 a0 = *(const float4*)(ap);
    float4 a1 = *(const float4*)(ap + 4);
    u32x4 b0 = *(const u32x4*)(wtrow + kt * 64);
    u32x4 b1 = *(const u32x4*)(wtrow + kt * 64 + 8);
    alignas(16) unsigned short o[8];
    float vv[8] = {a0.x, a0.y, a0.z, a0.w, a1.x, a1.y, a1.z, a1.w};
#pragma unroll
    for (int j = 0; j < 8; ++j) {
      unsigned short hi = bf16_rne(vv[j]);
      o[j] = (creg == 1) ? bf16_rne(vv[j] - bf16_to_f(hi)) : hi;
    }
    __syncthreads();  // previous iter's LDS reads done
    *(u32x4*)&As[arow * LDA + aoct * 8] = *(u32x4*)o;
    *(u32x4*)&Bs[brow * LDA + bq * 16] = b0;
    *(u32x4*)&Bs[brow * LDA + bq * 16 + 8] = b1;
    __syncthreads();
#pragma unroll
    for (int kk = 0; kk < 2; ++kk) {
      bf16x8 af[4], bf[2];
#pragma unroll
      for (int mi = 0; mi < 4; ++mi)
        af[mi] = *(const bf16x8*)&As[(wr * 64 + mi * 16 + (lane & 15)) * LDA + kk * 32 + (lane >> 4) * 8];
#pragma unroll
      for (int ni = 0; ni < 2; ++ni)
        bf[ni] = *(const bf16x8*)&Bs[(wc * 32 + ni * 16 + (lane & 15)) * LDA + kk * 32 + (lane >> 4) * 8];
#pragma unroll
      for (int mi = 0; mi < 4; ++mi)
#pragma unroll
        for (int ni = 0; ni < 2; ++ni)
          acc[mi][ni] = __builtin_amdgcn_mfma_f32_16x16x32_bf16(af[mi], bf[ni], acc[mi][ni], 0, 0, 0);
    }
  }
  int r0 = (lane >> 4) * 4, c0 = lane & 15;
#pragma unroll
  for (int mi = 0; mi < 4; ++mi) {
    int rowb = mt * 128 + wr * 64 + mi * 16 + r0;
#pragma unroll
    for (int ni = 0; ni < 2; ++ni) {
      int col = nt * 256 + wc * 32 + ni * 16 + c0;
#pragma unroll
      for (int r = 0; r < 4; ++r)
        drive[(size_t)(rowb + r) * H_ + col] = acc[mi][ni][r];
    }
  }
}

__global__ __launch_bounds__(1024, 1) void k_gemm(const float* __restrict__ x,
                                                  const unsigned short* __restrict__ Wt,
                                                  float* __restrict__ drive, int t0, int Tc) {
  __shared__ GemmSmem g;
  gemm_body(x, Wt, drive, t0, Tc, blockIdx.x, threadIdx.x, g.As, g.Bs);
}

// ---------------- one RSNN step (R11 structure, proven) ---------------------------------------
__device__ __forceinline__ void step_one(
    float dcur, int cur, int tid, int lane, unsigned wvu, unsigned myhi, float bias,
    const unsigned int* __restrict__ csr, int* accL, unsigned int* listL, unsigned int* fcL,
    float& v, float& s, float& cnt) {
  unsigned F = (unsigned)__builtin_amdgcn_readfirstlane((int)fcL[cur]);
  unsigned lo = (F * wvu) >> 4;
  unsigned hi = (F * (wvu + 1u)) >> 4;
  for (unsigned i0 = lo; i0 < hi; i0 += 8u) {
    unsigned idx = i0 + ((unsigned)lane & 7u);
    unsigned packed = listL[idx < hi ? idx : (hi - 1u)];  // one ds_read per 8 slots
#define EDECL(n) unsigned e##n = (i0 + n##u < hi) ? (unsigned)__builtin_amdgcn_readlane((int)packed, n) : 1024u; \
                 unsigned ea##n = 0u, eb##n = 0u;
    EDECL(0) EDECL(1) EDECL(2) EDECL(3) EDECL(4) EDECL(5) EDECL(6) EDECL(7)
#undef EDECL
#define ELOAD(n) if (e##n != 1024u) { \
      const unsigned int* rp = csr + ((size_t)(e##n & 1023u) << 7); \
      ea##n = rp[lane]; \
      if (e##n & 4096u) eb##n = rp[64 + lane]; }
    ELOAD(0) ELOAD(1) ELOAD(2) ELOAD(3) ELOAD(4) ELOAD(5) ELOAD(6) ELOAD(7)
#undef ELOAD
#define EATOM(n) if (e##n != 1024u) { \
      atomicAdd(&accL[ea##n & 1023u], ((int)ea##n) >> 10); \
      if (e##n & 4096u) atomicAdd(&accL[eb##n & 1023u], ((int)eb##n) >> 10); }
    EATOM(0) EATOM(1) EATOM(2) EATOM(3) EATOM(4) EATOM(5) EATOM(6) EATOM(7)
#undef EATOM
  }
  __syncthreads();
  int ri = accL[tid];
  accL[tid] = 0;
  v = BETA * v + (dcur + bias) + (float)ri * 1.1920929e-7f;  // 2^-23
  bool f = v > THRESH;
  v -= f ? THRESH : 0.f;
  cnt += f ? 1.f : 0.f;
  s = f ? 1.f : 0.f;
  unsigned long long bb = __ballot(f);
  unsigned n = (unsigned)__popcll(bb);
  unsigned pos = (unsigned)__popcll(bb & ((1ull << lane) - 1ull));
  unsigned wb = 0;
  if (lane == 0) wb = atomicAdd(&fcL[cur ^ 1], n);
  wb = (unsigned)__builtin_amdgcn_readfirstlane((int)wb);
  if (f) listL[wb + pos] = (unsigned)tid | myhi;
  if (tid == 0) fcL[cur] = 0;
  __syncthreads();
}

// ---------------- scan body (R11 structure, proven; parameterized smem) -----------------------
__device__ __forceinline__ void scan_body(
    const float* __restrict__ drive, const unsigned int* __restrict__ csr,
    const unsigned int* __restrict__ rowhi,
    const float* __restrict__ h_bias, const float* __restrict__ W_out,
    const float* __restrict__ b_out,
    float* __restrict__ state_v, float* __restrict__ state_s, float* __restrict__ state_c,
    float* __restrict__ out, int t0, int Tc, int last, int b, int tid, ScanSmem& sm) {
  int lane = tid & 63;
  unsigned wvu = (unsigned)__builtin_amdgcn_readfirstlane(tid >> 6);
  float bias = h_bias[tid];
  unsigned myhi = rowhi[tid] << 12;
  float v, s, cnt;
  if (t0 == 0) { v = 0.f; s = 0.f; cnt = 0.f; }
  else { v = state_v[b * H_ + tid]; s = state_s[b * H_ + tid]; cnt = state_c[b * H_ + tid]; }
  sm.accL[tid] = 0;
  if (tid < 2) sm.fcL[tid] = 0;
  __syncthreads();
  {  // initial firing list from carried state
    bool f0 = s > 0.f;
    unsigned long long bb = __ballot(f0);
    unsigned n = (unsigned)__popcll(bb);
    unsigned pos = (unsigned)__popcll(bb & ((1ull << lane) - 1ull));
    unsigned wb = 0;
    if (lane == 0) wb = atomicAdd(&sm.fcL[0], n);
    wb = (unsigned)__builtin_amdgcn_readfirstlane((int)wb);
    if (f0) sm.listL[wb + pos] = (unsigned)tid | myhi;
  }
  __syncthreads();
  const float* dptr = drive + (size_t)b * Tc * H_ + tid;
  for (int t8 = 0; t8 < Tc; t8 += 8) {
    float dd0 = (t8 + 0 < Tc) ? dptr[(size_t)(t8 + 0) * H_] : 0.f;
    float dd1 = (t8 + 1 < Tc) ? dptr[(size_t)(t8 + 1) * H_] : 0.f;
    float dd2 = (t8 + 2 < Tc) ? dptr[(size_t)(t8 + 2) * H_] : 0.f;
    float dd3 = (t8 + 3 < Tc) ? dptr[(size_t)(t8 + 3) * H_] : 0.f;
    float dd4 = (t8 + 4 < Tc) ? dptr[(size_t)(t8 + 4) * H_] : 0.f;
    float dd5 = (t8 + 5 < Tc) ? dptr[(size_t)(t8 + 5) * H_] : 0.f;
    float dd6 = (t8 + 6 < Tc) ? dptr[(size_t)(t8 + 6) * H_] : 0.f;
    float dd7 = (t8 + 7 < Tc) ? dptr[(size_t)(t8 + 7) * H_] : 0.f;
#define STEP(s_) if (t8 + s_ < Tc) \
    step_one(dd##s_, (s_ & 1), tid, lane, wvu, myhi, bias, csr, sm.accL, sm.listL, sm.fcL, v, s, cnt);
    STEP(0) STEP(1) STEP(2) STEP(3) STEP(4) STEP(5) STEP(6) STEP(7)
#undef STEP
  }
  if (!last) {
    state_v[b * H_ + tid] = v; state_s[b * H_ + tid] = s; state_c[b * H_ + tid] = cnt;
  } else {
    sm.red[tid] = cnt;
    __syncthreads();
    if (tid < 352) {
      int o = tid >> 5, seg = tid & 31;
      float p = 0.f;
      for (int j = 0; j < 32; ++j) {
        int hh = seg * 32 + j;
        p += sm.red[hh] * W_out[hh * O_ + o];
      }
      sm.part[tid] = p;
    }
    __syncthreads();
    if (tid < O_) {
      float sum = 0.f;
      for (int g = 0; g < 32; ++g) sum += sm.part[(tid << 5) + g];
      out[b * O_ + tid] = b_out[tid] + sum * (1.0f / (float)T_);
    }
  }
}

__global__ __launch_bounds__(1024, 1) void k_rsnn(
    const float* __restrict__ drive, const unsigned int* __restrict__ csr,
    const unsigned int* __restrict__ rowhi,
    const float* __restrict__ h_bias, const float* __restrict__ W_out,
    const float* __restrict__ b_out,
    float* __restrict__ state_v, float* __restrict__ state_s, float* __restrict__ state_c,
    float* __restrict__ out, int t0, int Tc, int last) {
  __shared__ ScanSmem sm;
  scan_body(drive, csr, rowhi, h_bias, W_out, b_out, state_v, state_s, state_c, out,
            t0, Tc, last, blockIdx.x, threadIdx.x, sm);
}

// ---------------- fused: blocks 0-127 scan chunk c; blocks 128+ GEMM chunk c+1 ----------------
__global__ __launch_bounds__(1024, 1) void k_fused(
    const float* __restrict__ drive_s, const unsigned int* __restrict__ csr,
    const unsigned int* __restrict__ rowhi,
    const float* __restrict__ h_bias, const float* __restrict__ W_out,
    const float* __restrict__ b_out,
    float* __restrict__ state_v, float* __restrict__ state_s, float* __restrict__ state_c,
    float* __restrict__ out, int t0s, int Tcs,
    const float* __restrict__ x, const unsigned short* __restrict__ Wt,
    float* __restrict__ drive_g, int t0g, int Tcg) {
  __shared__ FusedSmem sm;
  if (blockIdx.x < 128) {
    scan_body(drive_s, csr, rowhi, h_bias, W_out, b_out, state_v, state_s, state_c, out,
              t0s, Tcs, 0, blockIdx.x, threadIdx.x, sm.s);
  } else {
    gemm_body(x, Wt, drive_g, t0g, Tcg, blockIdx.x - 128, threadIdx.x, sm.g.As, sm.g.Bs);
  }
}

extern "C" void kernel_launch(void* const* d_in, const int* in_sizes, int n_in,
                              void* d_out, int out_size, void* d_ws, size_t ws_size,
                              hipStream_t stream) {
  (void)in_sizes; (void)n_in; (void)out_size;
  const float* x = (const float*)d_in[0];
  const float* W_in = (const float*)d_in[1];
  const float* W_rec = (const float*)d_in[2];
  const float* W_out = (const float*)d_in[3];
  const float* h_bias = (const float*)d_in[4];
  const float* b_out = (const float*)d_in[5];
  const float* mask = (const float*)d_in[6];
  float* out = (float*)d_out;

  char* ws = (char*)d_ws;
  size_t off = 0;
  auto alloc = [&](size_t bytes) {
    void* p = ws + off;
    off = (off + bytes + 255) & ~(size_t)255;
    return p;
  };
  unsigned short* Wt = (unsigned short*)alloc((size_t)H_ * K2_ * 2);
  unsigned int* csr = (unsigned int*)alloc((size_t)H_ * 128 * 4);
  unsigned int* rowhi = (unsigned int*)alloc((size_t)H_ * 4);
  float* st_v = (float*)alloc((size_t)B_ * H_ * 4);
  float* st_s = (float*)alloc((size_t)B_ * H_ * 4);
  float* st_c = (float*)alloc((size_t)B_ * H_ * 4);
  size_t fixed = off;

  size_t avail = ws_size > fixed ? ws_size - fixed : 0;
  const size_t per_t = (size_t)128 * 1024 * 4;  // 512 KB per timestep of drive
  int tcmax = (int)(avail / (2 * per_t));
  if (tcmax > 192) tcmax = 192;
  if (tcmax < 8) tcmax = 8;
  float* driveA = (float*)alloc((size_t)tcmax * per_t);
  float* driveB = (float*)alloc((size_t)tcmax * per_t);

  // geometric ramp: small first chunk (cheap GEMM0), big last chunk (cheap standalone scan)
  int sizes[64];
  int C = 0, left = T_, sgrow = 24;
  if (sgrow > tcmax) sgrow = tcmax;
  while (left > 0 && C < 64) {
    int take;
    int absorb = sgrow * 2 < tcmax ? sgrow * 2 : tcmax;
    if (left <= absorb) take = left < tcmax ? left : tcmax;
    else take = sgrow;
    sizes[C++] = take;
    left -= take;
    sgrow = sgrow + sgrow / 2;
    if (sgrow > tcmax) sgrow = tcmax;
  }
  int starts[64];
  { int t = 0; for (int c = 0; c < C; ++c) { starts[c] = t; t += sizes[c]; } }

  k_prep<<<dim3(256 + 6 * 1024), dim3(256), 0, stream>>>(W_rec, mask, W_in, csr, rowhi, Wt);

  {  // GEMM for chunk 0 (full machine)
    k_gemm<<<dim3(((sizes[0] + 7) / 8) * 32), dim3(1024), 0, stream>>>(x, Wt, driveA, 0, sizes[0]);
  }
  for (int c = 0; c < C; ++c) {
    int t0 = starts[c], tc = sizes[c];
    float* bufS = (c & 1) ? driveB : driveA;
    if (c + 1 < C) {
      int t0n = starts[c + 1], tcn = sizes[c + 1];
      float* bufG = ((c + 1) & 1) ? driveB : driveA;
      int gblocks = ((tcn + 7) / 8) * 32;
      k_fused<<<dim3(128 + gblocks), dim3(1024), 0, stream>>>(
          bufS, csr, rowhi, h_bias, W_out, b_out, st_v, st_s, st_c, out, t0, tc,
          x, Wt, bufG, t0n, tcn);
    } else {
      k_rsnn<<<dim3(128), dim3(1024), 0, stream>>>(bufS, csr, rowhi, h_bias, W_out, b_out,
                                                   st_v, st_s, st_c, out, t0, tc, 1);
    }
  }
}

// Round 14
// 844.361 us; speedup vs baseline: 1.0529x; 1.0529x over previous
//
#include <hip/hip_runtime.h>
#include <cstdint>
#include <cstddef>

#define B_ 128
#define T_ 500
#define I_ 512
#define H_ 1024
#define O_ 11
#define BETA 0.9f
#define THRESH 1.0f
#define K2_ 1536  // 3 regions of 512: [xh*wh | xl*wh | xh*wl]
#define LDA 72

typedef __attribute__((ext_vector_type(4))) float f32x4;
typedef __attribute__((ext_vector_type(8))) short bf16x8;
typedef __attribute__((ext_vector_type(4))) unsigned int u32x4;

struct ScanSmem {
  int accL[H_];
  unsigned int listL[H_];
  unsigned int fcL[2];
  float red[H_];
  float part[352];
};
struct GemmSmem {
  alignas(16) unsigned short As[128 * LDA];
  alignas(16) unsigned short Bs[256 * LDA];
};
union FusedSmem { ScanSmem s; GemmSmem g; };

__device__ __forceinline__ unsigned short bf16_rne(float f) {
  unsigned int u = __float_as_uint(f);
  unsigned int r = u + 0x7FFFu + ((u >> 16) & 1u);
  return (unsigned short)(r >> 16);
}
__device__ __forceinline__ float bf16_to_f(unsigned short h) {
  return __uint_as_float(((unsigned int)h) << 16);
}

// ---------------- merged prep: blocks 0-255 build CSR; blocks 256+ build Wt -------------------
__global__ void k_prep(const float* __restrict__ W_rec, const float* __restrict__ mask,
                       const float* __restrict__ W_in,
                       unsigned int* __restrict__ csr, unsigned int* __restrict__ rowhi,
                       unsigned short* __restrict__ Wt) {
  int id = blockIdx.x;
  int tid = threadIdx.x;
  if (id < 256) {
    int r = id * 4 + (tid >> 6);
    int lane = tid & 63;
    unsigned cnt = 0;
    const float* mrow = mask + (size_t)r * H_;
    const float* wrow = W_rec + (size_t)r * H_;
    for (int c = 0; c < 16; ++c) {
      float m = mrow[c * 64 + lane];
      bool nz = (m != 0.f);
      unsigned long long bb = __ballot(nz);
      unsigned pos = cnt + (unsigned)__popcll(bb & ((1ull << lane) - 1ull));
      if (nz) {
        float w = wrow[c * 64 + lane] * m;
        int wi = __float2int_rn(w * 8388608.f);  // 2^23
        wi = wi > 2097151 ? 2097151 : (wi < -2097151 ? -2097151 : wi);
        if (pos < 128u) csr[((size_t)r << 7) + pos] = (((unsigned)wi) << 10) | (unsigned)(c * 64 + lane);
      }
      cnt += (unsigned)__popcll(bb);
    }
    for (unsigned p = (cnt > 128u ? 128u : cnt) + (unsigned)lane; p < 128u; p += 64u)
      csr[((size_t)r << 7) + p] = (p & 63u);
    if (lane == 0) rowhi[r] = (cnt > 64u) ? 1u : 0u;
  } else {
    int wid = id - 256;
    int n = wid / 6, kblk = wid - n * 6;
    int k2 = kblk * 256 + tid;
    int i = k2 & 511;
    int c = k2 >> 9;
    float w = W_in[i * H_ + n];
    unsigned short hi = bf16_rne(w);
    unsigned short v = (c == 2) ? bf16_rne(w - bf16_to_f(hi)) : hi;
    Wt[(size_t)n * K2_ + k2] = v;
  }
}

// ---------------- GEMM body: 1024 threads / 16 waves, 128x256 tile, 64x32 per wave ------------
__device__ __forceinline__ void gemm_body(const float* __restrict__ x,
                                          const unsigned short* __restrict__ Wt,
                                          float* __restrict__ drive, int t0, int Tc,
                                          int id, int tid,
                                          unsigned short* As, unsigned short* Bs) {
  int mt = (id >> 5) * 8 + (id & 7);  // XCD affinity: same mt -> ids equal mod 8
  int nt = (id >> 3) & 3;
  if (mt >= Tc) return;
  int lane = tid & 63, w = tid >> 6;
  int wr = w >> 3, wc = w & 7;  // 2 x 8 wave grid, each 64x32
  f32x4 acc[4][2] = {};
  int arow = tid >> 3, aoct = tid & 7;  // A stage: 128 rows x 8 thr x 8 f32
  int brow = tid >> 2, bq = tid & 3;    // B stage: 256 rows x 4 thr x 16 bf16
  int rr = mt * 128 + arow;
  int bb = rr / Tc, tt = rr - bb * Tc;
  const float* xrow = x + ((size_t)(bb * T_ + t0 + tt)) * I_ + aoct * 8;
  const unsigned short* wtrow = Wt + (size_t)(nt * 256 + brow) * K2_ + bq * 16;
  for (int kt = 0; kt < K2_ / 64; ++kt) {
    int creg = kt >> 3;         // 0:xh 1:xl 2:xh (wave-uniform)
    const float* ap = xrow + (kt & 7) * 64;
    float4 a0 = *(const float4*)(ap);
    float4 a1 = *(const float4*)(ap + 4);
    u32x4 b0 = *(const u32x4*)(wtrow + kt * 64);
    u32x4 b1 = *(const u32x4*)(wtrow + kt * 64 + 8);
    alignas(16) unsigned short o[8];
    float vv[8] = {a0.x, a0.y, a0.z, a0.w, a1.x, a1.y, a1.z, a1.w};
#pragma unroll
    for (int j = 0; j < 8; ++j) {
      unsigned short hi = bf16_rne(vv[j]);
      o[j] = (creg == 1) ? bf16_rne(vv[j] - bf16_to_f(hi)) : hi;
    }
    __syncthreads();  // previous iter's LDS reads done
    *(u32x4*)&As[arow * LDA + aoct * 8] = *(u32x4*)o;
    *(u32x4*)&Bs[brow * LDA + bq * 16] = b0;
    *(u32x4*)&Bs[brow * LDA + bq * 16 + 8] = b1;
    __syncthreads();
#pragma unroll
    for (int kk = 0; kk < 2; ++kk) {
      bf16x8 af[4], bf[2];
#pragma unroll
      for (int mi = 0; mi < 4; ++mi)
        af[mi] = *(const bf16x8*)&As[(wr * 64 + mi * 16 + (lane & 15)) * LDA + kk * 32 + (lane >> 4) * 8];
#pragma unroll
      for (int ni = 0; ni < 2; ++ni)
        bf[ni] = *(const bf16x8*)&Bs[(wc * 32 + ni * 16 + (lane & 15)) * LDA + kk * 32 + (lane >> 4) * 8];
#pragma unroll
      for (int mi = 0; mi < 4; ++mi)
#pragma unroll
        for (int ni = 0; ni < 2; ++ni)
          acc[mi][ni] = __builtin_amdgcn_mfma_f32_16x16x32_bf16(af[mi], bf[ni], acc[mi][ni], 0, 0, 0);
    }
  }
  int r0 = (lane >> 4) * 4, c0 = lane & 15;
#pragma unroll
  for (int mi = 0; mi < 4; ++mi) {
    int rowb = mt * 128 + wr * 64 + mi * 16 + r0;
#pragma unroll
    for (int ni = 0; ni < 2; ++ni) {
      int col = nt * 256 + wc * 32 + ni * 16 + c0;
#pragma unroll
      for (int r = 0; r < 4; ++r)
        drive[(size_t)(rowb + r) * H_ + col] = acc[mi][ni][r];
    }
  }
}

__global__ __launch_bounds__(1024, 1) void k_gemm(const float* __restrict__ x,
                                                  const unsigned short* __restrict__ Wt,
                                                  float* __restrict__ drive, int t0, int Tc) {
  __shared__ GemmSmem g;
  gemm_body(x, Wt, drive, t0, Tc, blockIdx.x, threadIdx.x, g.As, g.Bs);
}

// ---------------- one RSNN step (R11 structure, proven) ---------------------------------------
__device__ __forceinline__ void step_one(
    float dcur, int cur, int tid, int lane, unsigned wvu, unsigned myhi, float bias,
    const unsigned int* __restrict__ csr, int* accL, unsigned int* listL, unsigned int* fcL,
    float& v, float& s, float& cnt) {
  unsigned F = (unsigned)__builtin_amdgcn_readfirstlane((int)fcL[cur]);
  unsigned lo = (F * wvu) >> 4;
  unsigned hi = (F * (wvu + 1u)) >> 4;
  for (unsigned i0 = lo; i0 < hi; i0 += 8u) {
    unsigned idx = i0 + ((unsigned)lane & 7u);
    unsigned packed = listL[idx < hi ? idx : (hi - 1u)];  // one ds_read per 8 slots
#define EDECL(n) unsigned e##n = (i0 + n##u < hi) ? (unsigned)__builtin_amdgcn_readlane((int)packed, n) : 1024u; \
                 unsigned ea##n = 0u, eb##n = 0u;
    EDECL(0) EDECL(1) EDECL(2) EDECL(3) EDECL(4) EDECL(5) EDECL(6) EDECL(7)
#undef EDECL
#define ELOAD(n) if (e##n != 1024u) { \
      const unsigned int* rp = csr + ((size_t)(e##n & 1023u) << 7); \
      ea##n = rp[lane]; \
      if (e##n & 4096u) eb##n = rp[64 + lane]; }
    ELOAD(0) ELOAD(1) ELOAD(2) ELOAD(3) ELOAD(4) ELOAD(5) ELOAD(6) ELOAD(7)
#undef ELOAD
#define EATOM(n) if (e##n != 1024u) { \
      atomicAdd(&accL[ea##n & 1023u], ((int)ea##n) >> 10); \
      if (e##n & 4096u) atomicAdd(&accL[eb##n & 1023u], ((int)eb##n) >> 10); }
    EATOM(0) EATOM(1) EATOM(2) EATOM(3) EATOM(4) EATOM(5) EATOM(6) EATOM(7)
#undef EATOM
  }
  __syncthreads();
  int ri = accL[tid];
  accL[tid] = 0;
  v = BETA * v + (dcur + bias) + (float)ri * 1.1920929e-7f;  // 2^-23
  bool f = v > THRESH;
  v -= f ? THRESH : 0.f;
  cnt += f ? 1.f : 0.f;
  s = f ? 1.f : 0.f;
  unsigned long long bb = __ballot(f);
  unsigned n = (unsigned)__popcll(bb);
  unsigned pos = (unsigned)__popcll(bb & ((1ull << lane) - 1ull));
  unsigned wb = 0;
  if (lane == 0) wb = atomicAdd(&fcL[cur ^ 1], n);
  wb = (unsigned)__builtin_amdgcn_readfirstlane((int)wb);
  if (f) listL[wb + pos] = (unsigned)tid | myhi;
  if (tid == 0) fcL[cur] = 0;
  __syncthreads();
}

// ---------------- scan body (R11 structure, proven; parameterized smem) -----------------------
__device__ __forceinline__ void scan_body(
    const float* __restrict__ drive, const unsigned int* __restrict__ csr,
    const unsigned int* __restrict__ rowhi,
    const float* __restrict__ h_bias, const float* __restrict__ W_out,
    const float* __restrict__ b_out,
    float* __restrict__ state_v, float* __restrict__ state_s, float* __restrict__ state_c,
    float* __restrict__ out, int t0, int Tc, int last, int b, int tid, ScanSmem& sm) {
  int lane = tid & 63;
  unsigned wvu = (unsigned)__builtin_amdgcn_readfirstlane(tid >> 6);
  float bias = h_bias[tid];
  unsigned myhi = rowhi[tid] << 12;
  float v, s, cnt;
  if (t0 == 0) { v = 0.f; s = 0.f; cnt = 0.f; }
  else { v = state_v[b * H_ + tid]; s = state_s[b * H_ + tid]; cnt = state_c[b * H_ + tid]; }
  sm.accL[tid] = 0;
  if (tid < 2) sm.fcL[tid] = 0;
  __syncthreads();
  {  // initial firing list from carried state
    bool f0 = s > 0.f;
    unsigned long long bb = __ballot(f0);
    unsigned n = (unsigned)__popcll(bb);
    unsigned pos = (unsigned)__popcll(bb & ((1ull << lane) - 1ull));
    unsigned wb = 0;
    if (lane == 0) wb = atomicAdd(&sm.fcL[0], n);
    wb = (unsigned)__builtin_amdgcn_readfirstlane((int)wb);
    if (f0) sm.listL[wb + pos] = (unsigned)tid | myhi;
  }
  __syncthreads();
  const float* dptr = drive + (size_t)b * Tc * H_ + tid;
  for (int t8 = 0; t8 < Tc; t8 += 8) {
    float dd0 = (t8 + 0 < Tc) ? dptr[(size_t)(t8 + 0) * H_] : 0.f;
    float dd1 = (t8 + 1 < Tc) ? dptr[(size_t)(t8 + 1) * H_] : 0.f;
    float dd2 = (t8 + 2 < Tc) ? dptr[(size_t)(t8 + 2) * H_] : 0.f;
    float dd3 = (t8 + 3 < Tc) ? dptr[(size_t)(t8 + 3) * H_] : 0.f;
    float dd4 = (t8 + 4 < Tc) ? dptr[(size_t)(t8 + 4) * H_] : 0.f;
    float dd5 = (t8 + 5 < Tc) ? dptr[(size_t)(t8 + 5) * H_] : 0.f;
    float dd6 = (t8 + 6 < Tc) ? dptr[(size_t)(t8 + 6) * H_] : 0.f;
    float dd7 = (t8 + 7 < Tc) ? dptr[(size_t)(t8 + 7) * H_] : 0.f;
#define STEP(s_) if (t8 + s_ < Tc) \
    step_one(dd##s_, (s_ & 1), tid, lane, wvu, myhi, bias, csr, sm.accL, sm.listL, sm.fcL, v, s, cnt);
    STEP(0) STEP(1) STEP(2) STEP(3) STEP(4) STEP(5) STEP(6) STEP(7)
#undef STEP
  }
  if (!last) {
    state_v[b * H_ + tid] = v; state_s[b * H_ + tid] = s; state_c[b * H_ + tid] = cnt;
  } else {
    sm.red[tid] = cnt;
    __syncthreads();
    if (tid < 352) {
      int o = tid >> 5, seg = tid & 31;
      float p = 0.f;
      for (int j = 0; j < 32; ++j) {
        int hh = seg * 32 + j;
        p += sm.red[hh] * W_out[hh * O_ + o];
      }
      sm.part[tid] = p;
    }
    __syncthreads();
    if (tid < O_) {
      float sum = 0.f;
      for (int g = 0; g < 32; ++g) sum += sm.part[(tid << 5) + g];
      out[b * O_ + tid] = b_out[tid] + sum * (1.0f / (float)T_);
    }
  }
}

__global__ __launch_bounds__(1024, 1) void k_rsnn(
    const float* __restrict__ drive, const unsigned int* __restrict__ csr,
    const unsigned int* __restrict__ rowhi,
    const float* __restrict__ h_bias, const float* __restrict__ W_out,
    const float* __restrict__ b_out,
    float* __restrict__ state_v, float* __restrict__ state_s, float* __restrict__ state_c,
    float* __restrict__ out, int t0, int Tc, int last) {
  __shared__ ScanSmem sm;
  scan_body(drive, csr, rowhi, h_bias, W_out, b_out, state_v, state_s, state_c, out,
            t0, Tc, last, blockIdx.x, threadIdx.x, sm);
}

// ---------------- fused: blocks 0-127 scan chunk c; blocks 128+ GEMM chunk c+1 ----------------
__global__ __launch_bounds__(1024, 1) void k_fused(
    const float* __restrict__ drive_s, const unsigned int* __restrict__ csr,
    const unsigned int* __restrict__ rowhi,
    const float* __restrict__ h_bias, const float* __restrict__ W_out,
    const float* __restrict__ b_out,
    float* __restrict__ state_v, float* __restrict__ state_s, float* __restrict__ state_c,
    float* __restrict__ out, int t0s, int Tcs,
    const float* __restrict__ x, const unsigned short* __restrict__ Wt,
    float* __restrict__ drive_g, int t0g, int Tcg) {
  __shared__ FusedSmem sm;
  if (blockIdx.x < 128) {
    scan_body(drive_s, csr, rowhi, h_bias, W_out, b_out, state_v, state_s, state_c, out,
              t0s, Tcs, 0, blockIdx.x, threadIdx.x, sm.s);
  } else {
    gemm_body(x, Wt, drive_g, t0g, Tcg, blockIdx.x - 128, threadIdx.x, sm.g.As, sm.g.Bs);
  }
}

extern "C" void kernel_launch(void* const* d_in, const int* in_sizes, int n_in,
                              void* d_out, int out_size, void* d_ws, size_t ws_size,
                              hipStream_t stream) {
  (void)in_sizes; (void)n_in; (void)out_size;
  const float* x = (const float*)d_in[0];
  const float* W_in = (const float*)d_in[1];
  const float* W_rec = (const float*)d_in[2];
  const float* W_out = (const float*)d_in[3];
  const float* h_bias = (const float*)d_in[4];
  const float* b_out = (const float*)d_in[5];
  const float* mask = (const float*)d_in[6];
  float* out = (float*)d_out;

  char* ws = (char*)d_ws;
  size_t off = 0;
  auto alloc = [&](size_t bytes) {
    void* p = ws + off;
    off = (off + bytes + 255) & ~(size_t)255;
    return p;
  };
  unsigned short* Wt = (unsigned short*)alloc((size_t)H_ * K2_ * 2);
  unsigned int* csr = (unsigned int*)alloc((size_t)H_ * 128 * 4);
  unsigned int* rowhi = (unsigned int*)alloc((size_t)H_ * 4);
  float* st_v = (float*)alloc((size_t)B_ * H_ * 4);
  float* st_s = (float*)alloc((size_t)B_ * H_ * 4);
  float* st_c = (float*)alloc((size_t)B_ * H_ * 4);
  size_t fixed = off;

  size_t avail = ws_size > fixed ? ws_size - fixed : 0;
  const size_t per_t = (size_t)128 * 1024 * 4;  // 512 KB per timestep of drive
  int tcmax = (int)(avail / (2 * per_t));
  if (tcmax > 192) tcmax = 192;
  if (tcmax < 8) tcmax = 8;
  float* driveA = (float*)alloc((size_t)tcmax * per_t);
  float* driveB = (float*)alloc((size_t)tcmax * per_t);

  // C=4 schedule {64,128,128,180}: small exposed GEMM0, big cheap standalone last chunk.
  // Fall back to even splits if the workspace can't hold 180-step buffers.
  int sizes[8];
  int C;
  if (tcmax >= 180) {
    sizes[0] = 64; sizes[1] = 128; sizes[2] = 128; sizes[3] = 180; C = 4;
  } else {
    C = 0; int left = T_;
    while (left > 0 && C < 8) {
      int take = left < tcmax ? left : tcmax;
      sizes[C++] = take; left -= take;
    }
  }
  int starts[8];
  { int t = 0; for (int c = 0; c < C; ++c) { starts[c] = t; t += sizes[c]; } }

  k_prep<<<dim3(256 + 6 * 1024), dim3(256), 0, stream>>>(W_rec, mask, W_in, csr, rowhi, Wt);

  {  // GEMM for chunk 0 (full machine)
    k_gemm<<<dim3(((sizes[0] + 7) / 8) * 32), dim3(1024), 0, stream>>>(x, Wt, driveA, 0, sizes[0]);
  }
  for (int c = 0; c < C; ++c) {
    int t0 = starts[c], tc = sizes[c];
    float* bufS = (c & 1) ? driveB : driveA;
    if (c + 1 < C) {
      int t0n = starts[c + 1], tcn = sizes[c + 1];
      float* bufG = ((c + 1) & 1) ? driveB : driveA;
      int gblocks = ((tcn + 7) / 8) * 32;
      k_fused<<<dim3(128 + gblocks), dim3(1024), 0, stream>>>(
          bufS, csr, rowhi, h_bias, W_out, b_out, st_v, st_s, st_c, out, t0, tc,
          x, Wt, bufG, t0n, tcn);
    } else {
      k_rsnn<<<dim3(128), dim3(1024), 0, stream>>>(bufS, csr, rowhi, h_bias, W_out, b_out,
                                                   st_v, st_s, st_c, out, t0, tc, 1);
    }
  }
}